// Round 9
// baseline (268.801 us; speedup 1.0000x reference)
//
#include <hip/hip_runtime.h>

#define C_DIM 128
#define EPS 1e-5f
#define NHB 160          // hist/scatter blocks
#define MAXNB 512        // max dst>>7 bins (n <= 65536)

typedef __attribute__((ext_vector_type(8))) short short8;
typedef __attribute__((ext_vector_type(4))) float f32x4;

__device__ __forceinline__ unsigned bf16rn(float f) {
    unsigned u = __float_as_uint(f);
    return (u + 0x7fffu + ((u >> 16) & 1u)) >> 16;
}
__device__ __forceinline__ unsigned pack_bf16(float lo, float hi) {
    return bf16rn(lo) | (bf16rn(hi) << 16);
}
__device__ __forceinline__ float blo(unsigned u) { return __uint_as_float(u << 16); }
__device__ __forceinline__ float bhi(unsigned u) { return __uint_as_float(u & 0xffff0000u); }

// ---------------- K1: per-block histogram of dst>>7 (LDS atomics only) + weight prep
__global__ __launch_bounds__(256) void k_hist(const int* __restrict__ edst,
                                              int* __restrict__ gh, int nb, int e, int epb,
                                              const float* __restrict__ Wc,
                                              const float* __restrict__ Wfc,
                                              unsigned short* __restrict__ WcT,
                                              unsigned short* __restrict__ WT) {
    int b = blockIdx.x, t = threadIdx.x;
    if (b < NHB) {
        __shared__ int hist[MAXNB];
        for (int i = t; i < nb; i += 256) hist[i] = 0;
        __syncthreads();
        int base = b * epb;
        int end = min(e, base + epb);
        for (int i = base + t; i < end; i += 256)
            atomicAdd(&hist[edst[i] >> 7], 1);
        __syncthreads();
        for (int i = t; i < nb; i += 256) gh[i * NHB + b] = hist[i];
    } else {
        // prep: W_conv^T and W_fc^T in bf16 ([n][k] layouts)
        for (int tid = t; tid < 128 * 128; tid += 256) {
            int nc = tid >> 7, k = tid & 127;
            WcT[tid] = (unsigned short)bf16rn(Wc[k * C_DIM + nc]);
        }
        for (int tid = t; tid < 48 * 128; tid += 256) {
            int nc = tid >> 7, k = tid & 127;
            float v = (nc < 40) ? Wfc[k * 40 + nc] : 0.f;
            WT[tid] = (unsigned short)bf16rn(v);
        }
    }
}

// ---------------- K2: exclusive scan of gh (len = nb*NHB, single block) ----------
__global__ __launch_bounds__(1024) void k_scan(int* __restrict__ gh, int len) {
    __shared__ int ts[1024];
    int t = threadIdx.x;
    int c = (len + 1023) >> 10;
    int lo = t * c, hi = min(len, lo + c);
    int s = 0;
    for (int i = lo; i < hi; i++) s += gh[i];
    ts[t] = s;
    __syncthreads();
    for (int off = 1; off < 1024; off <<= 1) {
        int v = (t >= off) ? ts[t - off] : 0;
        __syncthreads();
        ts[t] += v;
        __syncthreads();
    }
    int run = (t > 0) ? ts[t - 1] : 0;
    for (int i = lo; i < hi; i++) { int v = gh[i]; gh[i] = run; run += v; }
}

// ---------------- K3 FAT: bucket scatter (LDS cursors, race-free) | gemm1 MFMA ----
__global__ __launch_bounds__(256) void k_fat(const int* __restrict__ esrc,
                                             const int* __restrict__ edst,
                                             const int* __restrict__ gh,
                                             long long* __restrict__ sorted,
                                             const float* __restrict__ x,
                                             const unsigned short* __restrict__ WcT,
                                             unsigned* __restrict__ hb,
                                             int nb, int e, int epb, int n) {
    int b = blockIdx.x, t = threadIdx.x;
    if (b < NHB) {
        __shared__ int cur[MAXNB];
        for (int i = t; i < nb; i += 256) cur[i] = gh[i * NHB + b];  // block-private ranges
        __syncthreads();
        int base = b * epb, end = min(e, base + epb);
        for (int i = base + t; i < end; i += 256) {
            int d = edst[i], s = esrc[i];
            int pos = atomicAdd(&cur[d >> 7], 1);  // LDS atomic: per-CU, cheap
            sorted[pos] = (((long long)d) << 32) | (unsigned int)s;
        }
    } else {
        // gemm1: h = bf16(x) @ bf16(W_conv) via MFMA, LDS-free (verified R8)
        int gb = b - NHB;
        int w = t >> 6, lane = t & 63;
        int rw = gb * 128 + w * 32;
        if (rw >= n) return;  // wave-uniform
        int mrow = lane & 15, quad = lane >> 4;
        f32x4 acc[2][8];
#pragma unroll
        for (int m = 0; m < 2; m++)
#pragma unroll
            for (int nt = 0; nt < 8; nt++) acc[m][nt] = (f32x4){0.f, 0.f, 0.f, 0.f};
        int r0 = rw + mrow;
        int r1 = rw + 16 + mrow;
        if (r0 >= n) r0 = n - 1;  // clamp; stores are guarded
        if (r1 >= n) r1 = n - 1;
#pragma unroll
        for (int ks = 0; ks < 4; ks++) {
            short8 A[2];
#pragma unroll
            for (int m = 0; m < 2; m++) {
                const float* px = &x[(long)(m ? r1 : r0) * C_DIM + ks * 32 + quad * 8];
                float4 xa = *(const float4*)px;
                float4 xb = *(const float4*)(px + 4);
                uint4 au;
                au.x = pack_bf16(xa.x, xa.y);
                au.y = pack_bf16(xa.z, xa.w);
                au.z = pack_bf16(xb.x, xb.y);
                au.w = pack_bf16(xb.z, xb.w);
                union { uint4 u; short8 s; } cv;
                cv.u = au;
                A[m] = cv.s;
            }
#pragma unroll
            for (int nt = 0; nt < 8; nt++) {
                short8 B = *(const short8*)&WcT[(nt * 16 + mrow) * 128 + ks * 32 + quad * 8];
                acc[0][nt] = __builtin_amdgcn_mfma_f32_16x16x32_bf16(A[0], B, acc[0][nt], 0, 0, 0);
                acc[1][nt] = __builtin_amdgcn_mfma_f32_16x16x32_bf16(A[1], B, acc[1][nt], 0, 0, 0);
            }
        }
        bool evenc = (mrow & 1) == 0;
#pragma unroll
        for (int m = 0; m < 2; m++)
#pragma unroll
            for (int nt = 0; nt < 8; nt++)
#pragma unroll
                for (int reg = 0; reg < 4; reg++) {
                    float v = acc[m][nt][reg];
                    float pv = __shfl_xor(v, 1);
                    int rr = rw + m * 16 + quad * 4 + reg;
                    if (evenc && rr < n)
                        hb[(long)rr * 64 + ((nt * 16 + mrow) >> 1)] = pack_bf16(v, pv);
                }
    }
}

// ---------------- K4: per-bucket in-LDS counting sort -> compact CSR + dinv -------
__global__ __launch_bounds__(256) void k_csr(const long long* __restrict__ sorted,
                                             const int* __restrict__ gh,
                                             int* __restrict__ bsrc,
                                             int* __restrict__ rowptr,
                                             float* __restrict__ dinv,
                                             int nb, int n, int e) {
    __shared__ int h[128], basep[128], cur[128];
    int b = blockIdx.x, t = threadIdx.x;
    int node0 = b << 7;
    int nloc = min(128, n - node0);
    int start = gh[b * NHB];
    int end = (b + 1 < nb) ? gh[(b + 1) * NHB] : e;
    if (t < 128) h[t] = 0;
    __syncthreads();
    for (int i = start + t; i < end; i += 256)
        atomicAdd(&h[(int)(sorted[i] >> 32) & 127], 1);
    __syncthreads();
    if (t < 128) basep[t] = h[t];
    __syncthreads();
    for (int off = 1; off < 128; off <<= 1) {
        int v = 0;
        if (t < 128 && t >= off) v = basep[t - off];
        __syncthreads();
        if (t < 128) basep[t] += v;
        __syncthreads();
    }
    int excl = (t < 128) ? (basep[t] - h[t]) : 0;  // exclusive prefix
    if (t < nloc) {
        rowptr[node0 + t] = start + excl;
        dinv[node0 + t] = rsqrtf((float)h[t] + 1.0f);  // +1 self-loop
    }
    if (b == nb - 1 && t == 0) rowptr[n] = e;
    if (t < 128) cur[t] = excl;
    __syncthreads();
    for (int i = start + t; i < end; i += 256) {
        long long pk = sorted[i];
        int dl = (int)(pk >> 32) & 127;
        int pos = atomicAdd(&cur[dl], 1);
        bsrc[start + pos] = (int)(pk & 0xffffffffLL);
    }
}

// ---------------- fused aggregate + bias + relu*x + LN + residual (compact CSR) ----
__global__ __launch_bounds__(256) void aggregate(const unsigned* __restrict__ hb,
                                                 const float* __restrict__ x,
                                                 const int* __restrict__ rowptr,
                                                 const int* __restrict__ bsrc,
                                                 const float* __restrict__ dinv,
                                                 const float* __restrict__ bconv,
                                                 const float* __restrict__ gamma,
                                                 const float* __restrict__ beta,
                                                 unsigned* __restrict__ zb, int n) {
    int wid = (blockIdx.x * blockDim.x + threadIdx.x) >> 6;
    if (wid >= n) return;  // wave-uniform
    int lane = threadIdx.x & 63;
    int sub = lane & 15, grp = lane >> 4;
    int i = wid;
    float di = dinv[i];
    int beg = rowptr[i], end = rowptr[i + 1];

    uint4 us = *(const uint4*)(hb + (long)i * 64 + sub * 4);
    float wself = (grp == 0) ? di * di : 0.f;
    float acc[8];
    acc[0] = wself * blo(us.x); acc[1] = wself * bhi(us.x);
    acc[2] = wself * blo(us.y); acc[3] = wself * bhi(us.y);
    acc[4] = wself * blo(us.z); acc[5] = wself * bhi(us.z);
    acc[6] = wself * blo(us.w); acc[7] = wself * bhi(us.w);

    int k = beg + grp;
    for (; k + 4 < end; k += 8) {  // 8 edges in flight per wave iteration
        int s0 = bsrc[k];
        int s1 = bsrc[k + 4];
        float w0 = dinv[s0] * di;
        float w1 = dinv[s1] * di;
        uint4 u0 = *(const uint4*)(hb + (long)s0 * 64 + sub * 4);
        uint4 u1 = *(const uint4*)(hb + (long)s1 * 64 + sub * 4);
        acc[0] += w0 * blo(u0.x); acc[1] += w0 * bhi(u0.x);
        acc[2] += w0 * blo(u0.y); acc[3] += w0 * bhi(u0.y);
        acc[4] += w0 * blo(u0.z); acc[5] += w0 * bhi(u0.z);
        acc[6] += w0 * blo(u0.w); acc[7] += w0 * bhi(u0.w);
        acc[0] += w1 * blo(u1.x); acc[1] += w1 * bhi(u1.x);
        acc[2] += w1 * blo(u1.y); acc[3] += w1 * bhi(u1.y);
        acc[4] += w1 * blo(u1.z); acc[5] += w1 * bhi(u1.z);
        acc[6] += w1 * blo(u1.w); acc[7] += w1 * bhi(u1.w);
    }
    for (; k < end; k += 4) {
        int s = bsrc[k];
        float w = dinv[s] * di;
        uint4 u = *(const uint4*)(hb + (long)s * 64 + sub * 4);
        acc[0] += w * blo(u.x); acc[1] += w * bhi(u.x);
        acc[2] += w * blo(u.y); acc[3] += w * bhi(u.y);
        acc[4] += w * blo(u.z); acc[5] += w * bhi(u.z);
        acc[6] += w * blo(u.w); acc[7] += w * bhi(u.w);
    }

#pragma unroll
    for (int j = 0; j < 8; j++) {
        acc[j] += __shfl_xor(acc[j], 16);
        acc[j] += __shfl_xor(acc[j], 32);
    }

    float4 bca = *(const float4*)&bconv[sub * 8];
    float4 bcb = *(const float4*)&bconv[sub * 8 + 4];
    float4 xa  = *(const float4*)&x[(long)i * C_DIM + sub * 8];
    float4 xb  = *(const float4*)&x[(long)i * C_DIM + sub * 8 + 4];
    float a[8], xv[8];
    xv[0] = xa.x; xv[1] = xa.y; xv[2] = xa.z; xv[3] = xa.w;
    xv[4] = xb.x; xv[5] = xb.y; xv[6] = xb.z; xv[7] = xb.w;
    float bc[8] = {bca.x, bca.y, bca.z, bca.w, bcb.x, bcb.y, bcb.z, bcb.w};
#pragma unroll
    for (int j = 0; j < 8; j++) a[j] = fmaxf(acc[j] + bc[j], 0.f) * xv[j];

    float s = a[0] + a[1] + a[2] + a[3] + a[4] + a[5] + a[6] + a[7];
#pragma unroll
    for (int off = 1; off < 16; off <<= 1) s += __shfl_xor(s, off);
    float mu = s * (1.0f / 128.0f);
    float d[8], v = 0.f;
#pragma unroll
    for (int j = 0; j < 8; j++) { d[j] = a[j] - mu; v += d[j] * d[j]; }
#pragma unroll
    for (int off = 1; off < 16; off <<= 1) v += __shfl_xor(v, off);
    float inv = rsqrtf(v * (1.0f / 128.0f) + EPS);

    if (grp == 0) {
        float4 ga = *(const float4*)&gamma[sub * 8];
        float4 gb = *(const float4*)&gamma[sub * 8 + 4];
        float4 ba = *(const float4*)&beta[sub * 8];
        float4 bb = *(const float4*)&beta[sub * 8 + 4];
        float g[8] = {ga.x, ga.y, ga.z, ga.w, gb.x, gb.y, gb.z, gb.w};
        float be[8] = {ba.x, ba.y, ba.z, ba.w, bb.x, bb.y, bb.z, bb.w};
        float o[8];
#pragma unroll
        for (int j = 0; j < 8; j++) o[j] = d[j] * inv * g[j] + be[j] + xv[j];
        uint4 p;
        p.x = pack_bf16(o[0], o[1]);
        p.y = pack_bf16(o[2], o[3]);
        p.z = pack_bf16(o[4], o[5]);
        p.w = pack_bf16(o[6], o[7]);
        *(uint4*)(zb + (long)i * 64 + sub * 4) = p;
    }
}

// ---------------- GEMM2: out = z @ W_fc + b_fc via bf16 MFMA, no LDS ----------------
__global__ __launch_bounds__(256) void gemm2(const unsigned short* __restrict__ zb,
                                             const unsigned short* __restrict__ WT,
                                             const float* __restrict__ bfc,
                                             float* __restrict__ out, int n) {
    int t = threadIdx.x;
    int w = t >> 6, lane = t & 63;
    int r0 = (blockIdx.x * 4 + w) * 64;
    if (r0 >= n) return;
    int mrow = lane & 15;
    int quad = lane >> 4;
    f32x4 acc[4][3];
#pragma unroll
    for (int m = 0; m < 4; m++)
#pragma unroll
        for (int nt = 0; nt < 3; nt++) acc[m][nt] = (f32x4){0.f, 0.f, 0.f, 0.f};
#pragma unroll
    for (int ks = 0; ks < 4; ks++) {
        short8 A[4], B[3];
#pragma unroll
        for (int m = 0; m < 4; m++) {
            int r = r0 + m * 16 + mrow;
            if (r >= n) r = n - 1;  // clamp (stores are guarded)
            A[m] = *(const short8*)&zb[(long)r * 128 + ks * 32 + quad * 8];
        }
#pragma unroll
        for (int nt = 0; nt < 3; nt++)
            B[nt] = *(const short8*)&WT[(nt * 16 + mrow) * 128 + ks * 32 + quad * 8];
#pragma unroll
        for (int m = 0; m < 4; m++)
#pragma unroll
            for (int nt = 0; nt < 3; nt++)
                acc[m][nt] = __builtin_amdgcn_mfma_f32_16x16x32_bf16(A[m], B[nt], acc[m][nt], 0, 0, 0);
    }
#pragma unroll
    for (int nt = 0; nt < 3; nt++) {
        int c = nt * 16 + mrow;
        if (c < 40) {
            float bias = bfc[c];
#pragma unroll
            for (int m = 0; m < 4; m++) {
#pragma unroll
                for (int reg = 0; reg < 4; reg++) {
                    int r = r0 + m * 16 + quad * 4 + reg;
                    if (r < n) out[(long)r * 40 + c] = acc[m][nt][reg] + bias;
                }
            }
        }
    }
}

extern "C" void kernel_launch(void* const* d_in, const int* in_sizes, int n_in,
                              void* d_out, int out_size, void* d_ws, size_t ws_size,
                              hipStream_t stream) {
    const float* x     = (const float*)d_in[0];
    const int*   ei    = (const int*)d_in[1];
    const float* Wc    = (const float*)d_in[2];
    const float* bc    = (const float*)d_in[3];
    const float* gamma = (const float*)d_in[4];
    const float* beta  = (const float*)d_in[5];
    const float* Wfc   = (const float*)d_in[6];
    const float* bfc   = (const float*)d_in[7];
    float* out = (float*)d_out;

    int N = in_sizes[0] / C_DIM;
    int E = in_sizes[1] / 2;
    const int* esrc = ei;
    const int* edst = ei + E;

    int nb  = (N + 127) >> 7;            // dst>>7 buckets (391 for N=50000)
    int epb = (E + NHB - 1) / NHB;       // edges per hist/scatter block (4000)

    char* p = (char*)d_ws;
    auto carve = [&](size_t bytes) {
        void* q = (void*)p;
        p += (bytes + 255) & ~(size_t)255;
        return q;
    };
    unsigned* hb        = (unsigned*)carve((size_t)N * 64 * 4);     // h bf16 pairs
    unsigned* zb        = (unsigned*)carve((size_t)N * 64 * 4);     // z bf16 pairs
    unsigned short* WcT = (unsigned short*)carve(128 * 128 * 2);    // W_conv^T bf16
    unsigned short* WT  = (unsigned short*)carve(48 * 128 * 2);     // W_fc^T bf16
    float* dinv         = (float*)carve((size_t)N * 4);
    int*   gh           = (int*)carve((size_t)nb * NHB * 4);        // [bin][blk] counts->prefix
    long long* sorted   = (long long*)carve((size_t)E * 8);         // bucketed (dst,src)
    int*   bsrc         = (int*)carve((size_t)E * 4);               // compact CSR payload
    int*   rowptr       = (int*)carve((size_t)(N + 1) * 4);

    // K1: histogram (LDS atomics only) + weight prep — no memset needed anywhere
    k_hist<<<NHB + 1, 256, 0, stream>>>(edst, gh, nb, E, epb, Wc, Wfc, WcT, WT);
    // K2: exclusive scan of (bin,blk) counts
    k_scan<<<1, 1024, 0, stream>>>(gh, nb * NHB);
    // K3: race-free bucket scatter (LDS cursors) | gemm1 MFMA backfill
    int g1 = (N + 127) / 128;
    k_fat<<<NHB + g1, 256, 0, stream>>>(esrc, edst, gh, sorted, x, WcT, hb, nb, E, epb, N);
    // K4: per-bucket in-LDS counting sort -> compact CSR + dinv
    k_csr<<<nb, 256, 0, stream>>>(sorted, gh, bsrc, rowptr, dinv, nb, N, E);

    aggregate<<<((size_t)N * 64 + 255) / 256, 256, 0, stream>>>(
        hb, x, rowptr, bsrc, dinv, bc, gamma, beta, zb, N);

    gemm2<<<(N / 64 + 4) / 4, 256, 0, stream>>>((const unsigned short*)zb, WT, bfc, out, N);
}

// Round 10
// 181.599 us; speedup vs baseline: 1.4802x; 1.4802x over previous
//
#include <hip/hip_runtime.h>

#define C_DIM 128
#define EPS 1e-5f
#define NHB 160          // hist/scatter blocks
#define MAXNB 512        // max dst>>7 bins (n <= 65536)

typedef __attribute__((ext_vector_type(8))) short short8;
typedef __attribute__((ext_vector_type(4))) float f32x4;

__device__ __forceinline__ unsigned bf16rn(float f) {
    unsigned u = __float_as_uint(f);
    return (u + 0x7fffu + ((u >> 16) & 1u)) >> 16;
}
__device__ __forceinline__ unsigned pack_bf16(float lo, float hi) {
    return bf16rn(lo) | (bf16rn(hi) << 16);
}
__device__ __forceinline__ float blo(unsigned u) { return __uint_as_float(u << 16); }
__device__ __forceinline__ float bhi(unsigned u) { return __uint_as_float(u & 0xffff0000u); }

// ---------------- K1: per-block histogram of dst>>7 (LDS atomics only) + weight prep
__global__ __launch_bounds__(256) void k_hist(const int* __restrict__ edst,
                                              int* __restrict__ gh, int nb, int e, int epb,
                                              const float* __restrict__ Wc,
                                              const float* __restrict__ Wfc,
                                              unsigned short* __restrict__ WcT,
                                              unsigned short* __restrict__ WT) {
    int b = blockIdx.x, t = threadIdx.x;
    if (b < NHB) {
        __shared__ int hist[MAXNB];
        for (int i = t; i < nb; i += 256) hist[i] = 0;
        __syncthreads();
        int base = b * epb;
        int end = min(e, base + epb);
        for (int i = base + t; i < end; i += 256)
            atomicAdd(&hist[edst[i] >> 7], 1);
        __syncthreads();
        for (int i = t; i < nb; i += 256) gh[i * NHB + b] = hist[i];
    } else {
        // prep: W_conv^T and W_fc^T in bf16 ([n][k] layouts)
        for (int tid = t; tid < 128 * 128; tid += 256) {
            int nc = tid >> 7, k = tid & 127;
            WcT[tid] = (unsigned short)bf16rn(Wc[k * C_DIM + nc]);
        }
        for (int tid = t; tid < 48 * 128; tid += 256) {
            int nc = tid >> 7, k = tid & 127;
            float v = (nc < 40) ? Wfc[k * 40 + nc] : 0.f;
            WT[tid] = (unsigned short)bf16rn(v);
        }
    }
}

// ---------------- K2a: per-bin sum (parallel over nb blocks) ----------------
__global__ __launch_bounds__(256) void k_scan_a(const int* __restrict__ gh,
                                                int* __restrict__ binsum, int nb) {
    __shared__ int ws[4];
    int bin = blockIdx.x, t = threadIdx.x;
    int v = (t < NHB) ? gh[bin * NHB + t] : 0;
#pragma unroll
    for (int off = 1; off < 64; off <<= 1) v += __shfl_xor(v, off);
    if ((t & 63) == 0) ws[t >> 6] = v;
    __syncthreads();
    if (t == 0) binsum[bin] = ws[0] + ws[1] + ws[2] + ws[3];
}

// ---------------- K2b: exclusive scan of bin sums (single small block) -------------
__global__ __launch_bounds__(512) void k_scan_b(int* __restrict__ binsum, int nb) {
    __shared__ int ts[512];
    int t = threadIdx.x;
    int v = (t < nb) ? binsum[t] : 0;
    ts[t] = v;
    __syncthreads();
    for (int off = 1; off < 512; off <<= 1) {
        int a = (t >= off) ? ts[t - off] : 0;
        __syncthreads();
        ts[t] += a;
        __syncthreads();
    }
    if (t < nb) binsum[t] = ts[t] - v;  // exclusive
}

// ---------------- K2c: per-bin exclusive scan + bin offset (parallel) --------------
__global__ __launch_bounds__(256) void k_scan_c(int* __restrict__ gh,
                                                const int* __restrict__ binsum, int nb) {
    __shared__ int ts[256];
    int bin = blockIdx.x, t = threadIdx.x;
    int v = (t < NHB) ? gh[bin * NHB + t] : 0;
    ts[t] = v;
    __syncthreads();
    for (int off = 1; off < 256; off <<= 1) {
        int a = (t >= off) ? ts[t - off] : 0;
        __syncthreads();
        ts[t] += a;
        __syncthreads();
    }
    if (t < NHB) gh[bin * NHB + t] = ts[t] - v + binsum[bin];
}

// ---------------- K3 FAT: bucket scatter (LDS cursors, race-free) | gemm1 MFMA ----
__global__ __launch_bounds__(256) void k_fat(const int* __restrict__ esrc,
                                             const int* __restrict__ edst,
                                             const int* __restrict__ gh,
                                             long long* __restrict__ sorted,
                                             const float* __restrict__ x,
                                             const unsigned short* __restrict__ WcT,
                                             unsigned* __restrict__ hb,
                                             int nb, int e, int epb, int n) {
    int b = blockIdx.x, t = threadIdx.x;
    if (b < NHB) {
        __shared__ int cur[MAXNB];
        for (int i = t; i < nb; i += 256) cur[i] = gh[i * NHB + b];  // block-private ranges
        __syncthreads();
        int base = b * epb, end = min(e, base + epb);
        for (int i = base + t; i < end; i += 256) {
            int d = edst[i], s = esrc[i];
            int pos = atomicAdd(&cur[d >> 7], 1);  // LDS atomic: per-CU, cheap
            sorted[pos] = (((long long)d) << 32) | (unsigned int)s;
        }
    } else {
        // gemm1: h = bf16(x) @ bf16(W_conv) via MFMA, LDS-free (verified R8)
        int gb = b - NHB;
        int w = t >> 6, lane = t & 63;
        int rw = gb * 128 + w * 32;
        if (rw >= n) return;  // wave-uniform
        int mrow = lane & 15, quad = lane >> 4;
        f32x4 acc[2][8];
#pragma unroll
        for (int m = 0; m < 2; m++)
#pragma unroll
            for (int nt = 0; nt < 8; nt++) acc[m][nt] = (f32x4){0.f, 0.f, 0.f, 0.f};
        int r0 = rw + mrow;
        int r1 = rw + 16 + mrow;
        if (r0 >= n) r0 = n - 1;  // clamp; stores are guarded
        if (r1 >= n) r1 = n - 1;
#pragma unroll
        for (int ks = 0; ks < 4; ks++) {
            short8 A[2];
#pragma unroll
            for (int m = 0; m < 2; m++) {
                const float* px = &x[(long)(m ? r1 : r0) * C_DIM + ks * 32 + quad * 8];
                float4 xa = *(const float4*)px;
                float4 xb = *(const float4*)(px + 4);
                uint4 au;
                au.x = pack_bf16(xa.x, xa.y);
                au.y = pack_bf16(xa.z, xa.w);
                au.z = pack_bf16(xb.x, xb.y);
                au.w = pack_bf16(xb.z, xb.w);
                union { uint4 u; short8 s; } cv;
                cv.u = au;
                A[m] = cv.s;
            }
#pragma unroll
            for (int nt = 0; nt < 8; nt++) {
                short8 B = *(const short8*)&WcT[(nt * 16 + mrow) * 128 + ks * 32 + quad * 8];
                acc[0][nt] = __builtin_amdgcn_mfma_f32_16x16x32_bf16(A[0], B, acc[0][nt], 0, 0, 0);
                acc[1][nt] = __builtin_amdgcn_mfma_f32_16x16x32_bf16(A[1], B, acc[1][nt], 0, 0, 0);
            }
        }
        bool evenc = (mrow & 1) == 0;
#pragma unroll
        for (int m = 0; m < 2; m++)
#pragma unroll
            for (int nt = 0; nt < 8; nt++)
#pragma unroll
                for (int reg = 0; reg < 4; reg++) {
                    float v = acc[m][nt][reg];
                    float pv = __shfl_xor(v, 1);
                    int rr = rw + m * 16 + quad * 4 + reg;
                    if (evenc && rr < n)
                        hb[(long)rr * 64 + ((nt * 16 + mrow) >> 1)] = pack_bf16(v, pv);
                }
    }
}

// ---------------- K4: per-bucket in-LDS counting sort -> compact CSR + dinv -------
__global__ __launch_bounds__(256) void k_csr(const long long* __restrict__ sorted,
                                             const int* __restrict__ gh,
                                             int* __restrict__ bsrc,
                                             int* __restrict__ rowptr,
                                             float* __restrict__ dinv,
                                             int nb, int n, int e) {
    __shared__ int h[128], basep[128], cur[128];
    int b = blockIdx.x, t = threadIdx.x;
    int node0 = b << 7;
    int nloc = min(128, n - node0);
    int start = gh[b * NHB];
    int end = (b + 1 < nb) ? gh[(b + 1) * NHB] : e;
    if (t < 128) h[t] = 0;
    __syncthreads();
    for (int i = start + t; i < end; i += 256)
        atomicAdd(&h[(int)(sorted[i] >> 32) & 127], 1);
    __syncthreads();
    if (t < 128) basep[t] = h[t];
    __syncthreads();
    for (int off = 1; off < 128; off <<= 1) {
        int v = 0;
        if (t < 128 && t >= off) v = basep[t - off];
        __syncthreads();
        if (t < 128) basep[t] += v;
        __syncthreads();
    }
    int excl = (t < 128) ? (basep[t] - h[t]) : 0;  // exclusive prefix
    if (t < nloc) {
        rowptr[node0 + t] = start + excl;
        dinv[node0 + t] = rsqrtf((float)h[t] + 1.0f);  // +1 self-loop
    }
    if (b == nb - 1 && t == 0) rowptr[n] = e;
    if (t < 128) cur[t] = excl;
    __syncthreads();
    for (int i = start + t; i < end; i += 256) {
        long long pk = sorted[i];
        int dl = (int)(pk >> 32) & 127;
        int pos = atomicAdd(&cur[dl], 1);
        bsrc[start + pos] = (int)(pk & 0xffffffffLL);
    }
}

// ---------------- fused aggregate + bias + relu*x + LN + residual (compact CSR) ----
__global__ __launch_bounds__(256) void aggregate(const unsigned* __restrict__ hb,
                                                 const float* __restrict__ x,
                                                 const int* __restrict__ rowptr,
                                                 const int* __restrict__ bsrc,
                                                 const float* __restrict__ dinv,
                                                 const float* __restrict__ bconv,
                                                 const float* __restrict__ gamma,
                                                 const float* __restrict__ beta,
                                                 unsigned* __restrict__ zb, int n) {
    int wid = (blockIdx.x * blockDim.x + threadIdx.x) >> 6;
    if (wid >= n) return;  // wave-uniform
    int lane = threadIdx.x & 63;
    int sub = lane & 15, grp = lane >> 4;
    int i = wid;
    float di = dinv[i];
    int beg = rowptr[i], end = rowptr[i + 1];

    uint4 us = *(const uint4*)(hb + (long)i * 64 + sub * 4);
    float wself = (grp == 0) ? di * di : 0.f;
    float acc[8];
    acc[0] = wself * blo(us.x); acc[1] = wself * bhi(us.x);
    acc[2] = wself * blo(us.y); acc[3] = wself * bhi(us.y);
    acc[4] = wself * blo(us.z); acc[5] = wself * bhi(us.z);
    acc[6] = wself * blo(us.w); acc[7] = wself * bhi(us.w);

    int k = beg + grp;
    for (; k + 4 < end; k += 8) {  // 8 edges in flight per wave iteration
        int s0 = bsrc[k];
        int s1 = bsrc[k + 4];
        float w0 = dinv[s0] * di;
        float w1 = dinv[s1] * di;
        uint4 u0 = *(const uint4*)(hb + (long)s0 * 64 + sub * 4);
        uint4 u1 = *(const uint4*)(hb + (long)s1 * 64 + sub * 4);
        acc[0] += w0 * blo(u0.x); acc[1] += w0 * bhi(u0.x);
        acc[2] += w0 * blo(u0.y); acc[3] += w0 * bhi(u0.y);
        acc[4] += w0 * blo(u0.z); acc[5] += w0 * bhi(u0.z);
        acc[6] += w0 * blo(u0.w); acc[7] += w0 * bhi(u0.w);
        acc[0] += w1 * blo(u1.x); acc[1] += w1 * bhi(u1.x);
        acc[2] += w1 * blo(u1.y); acc[3] += w1 * bhi(u1.y);
        acc[4] += w1 * blo(u1.z); acc[5] += w1 * bhi(u1.z);
        acc[6] += w1 * blo(u1.w); acc[7] += w1 * bhi(u1.w);
    }
    for (; k < end; k += 4) {
        int s = bsrc[k];
        float w = dinv[s] * di;
        uint4 u = *(const uint4*)(hb + (long)s * 64 + sub * 4);
        acc[0] += w * blo(u.x); acc[1] += w * bhi(u.x);
        acc[2] += w * blo(u.y); acc[3] += w * bhi(u.y);
        acc[4] += w * blo(u.z); acc[5] += w * bhi(u.z);
        acc[6] += w * blo(u.w); acc[7] += w * bhi(u.w);
    }

#pragma unroll
    for (int j = 0; j < 8; j++) {
        acc[j] += __shfl_xor(acc[j], 16);
        acc[j] += __shfl_xor(acc[j], 32);
    }

    float4 bca = *(const float4*)&bconv[sub * 8];
    float4 bcb = *(const float4*)&bconv[sub * 8 + 4];
    float4 xa  = *(const float4*)&x[(long)i * C_DIM + sub * 8];
    float4 xb  = *(const float4*)&x[(long)i * C_DIM + sub * 8 + 4];
    float a[8], xv[8];
    xv[0] = xa.x; xv[1] = xa.y; xv[2] = xa.z; xv[3] = xa.w;
    xv[4] = xb.x; xv[5] = xb.y; xv[6] = xb.z; xv[7] = xb.w;
    float bc[8] = {bca.x, bca.y, bca.z, bca.w, bcb.x, bcb.y, bcb.z, bcb.w};
#pragma unroll
    for (int j = 0; j < 8; j++) a[j] = fmaxf(acc[j] + bc[j], 0.f) * xv[j];

    float s = a[0] + a[1] + a[2] + a[3] + a[4] + a[5] + a[6] + a[7];
#pragma unroll
    for (int off = 1; off < 16; off <<= 1) s += __shfl_xor(s, off);
    float mu = s * (1.0f / 128.0f);
    float d[8], v = 0.f;
#pragma unroll
    for (int j = 0; j < 8; j++) { d[j] = a[j] - mu; v += d[j] * d[j]; }
#pragma unroll
    for (int off = 1; off < 16; off <<= 1) v += __shfl_xor(v, off);
    float inv = rsqrtf(v * (1.0f / 128.0f) + EPS);

    if (grp == 0) {
        float4 ga = *(const float4*)&gamma[sub * 8];
        float4 gb = *(const float4*)&gamma[sub * 8 + 4];
        float4 ba = *(const float4*)&beta[sub * 8];
        float4 bb = *(const float4*)&beta[sub * 8 + 4];
        float g[8] = {ga.x, ga.y, ga.z, ga.w, gb.x, gb.y, gb.z, gb.w};
        float be[8] = {ba.x, ba.y, ba.z, ba.w, bb.x, bb.y, bb.z, bb.w};
        float o[8];
#pragma unroll
        for (int j = 0; j < 8; j++) o[j] = d[j] * inv * g[j] + be[j] + xv[j];
        uint4 p;
        p.x = pack_bf16(o[0], o[1]);
        p.y = pack_bf16(o[2], o[3]);
        p.z = pack_bf16(o[4], o[5]);
        p.w = pack_bf16(o[6], o[7]);
        *(uint4*)(zb + (long)i * 64 + sub * 4) = p;
    }
}

// ---------------- GEMM2: out = z @ W_fc + b_fc via bf16 MFMA, no LDS ----------------
__global__ __launch_bounds__(256) void gemm2(const unsigned short* __restrict__ zb,
                                             const unsigned short* __restrict__ WT,
                                             const float* __restrict__ bfc,
                                             float* __restrict__ out, int n) {
    int t = threadIdx.x;
    int w = t >> 6, lane = t & 63;
    int r0 = (blockIdx.x * 4 + w) * 64;
    if (r0 >= n) return;
    int mrow = lane & 15;
    int quad = lane >> 4;
    f32x4 acc[4][3];
#pragma unroll
    for (int m = 0; m < 4; m++)
#pragma unroll
        for (int nt = 0; nt < 3; nt++) acc[m][nt] = (f32x4){0.f, 0.f, 0.f, 0.f};
#pragma unroll
    for (int ks = 0; ks < 4; ks++) {
        short8 A[4], B[3];
#pragma unroll
        for (int m = 0; m < 4; m++) {
            int r = r0 + m * 16 + mrow;
            if (r >= n) r = n - 1;  // clamp (stores are guarded)
            A[m] = *(const short8*)&zb[(long)r * 128 + ks * 32 + quad * 8];
        }
#pragma unroll
        for (int nt = 0; nt < 3; nt++)
            B[nt] = *(const short8*)&WT[(nt * 16 + mrow) * 128 + ks * 32 + quad * 8];
#pragma unroll
        for (int m = 0; m < 4; m++)
#pragma unroll
            for (int nt = 0; nt < 3; nt++)
                acc[m][nt] = __builtin_amdgcn_mfma_f32_16x16x32_bf16(A[m], B[nt], acc[m][nt], 0, 0, 0);
    }
#pragma unroll
    for (int nt = 0; nt < 3; nt++) {
        int c = nt * 16 + mrow;
        if (c < 40) {
            float bias = bfc[c];
#pragma unroll
            for (int m = 0; m < 4; m++) {
#pragma unroll
                for (int reg = 0; reg < 4; reg++) {
                    int r = r0 + m * 16 + quad * 4 + reg;
                    if (r < n) out[(long)r * 40 + c] = acc[m][nt][reg] + bias;
                }
            }
        }
    }
}

extern "C" void kernel_launch(void* const* d_in, const int* in_sizes, int n_in,
                              void* d_out, int out_size, void* d_ws, size_t ws_size,
                              hipStream_t stream) {
    const float* x     = (const float*)d_in[0];
    const int*   ei    = (const int*)d_in[1];
    const float* Wc    = (const float*)d_in[2];
    const float* bc    = (const float*)d_in[3];
    const float* gamma = (const float*)d_in[4];
    const float* beta  = (const float*)d_in[5];
    const float* Wfc   = (const float*)d_in[6];
    const float* bfc   = (const float*)d_in[7];
    float* out = (float*)d_out;

    int N = in_sizes[0] / C_DIM;
    int E = in_sizes[1] / 2;
    const int* esrc = ei;
    const int* edst = ei + E;

    int nb  = (N + 127) >> 7;            // dst>>7 buckets (391 for N=50000)
    int epb = (E + NHB - 1) / NHB;       // edges per hist/scatter block (4000)

    char* p = (char*)d_ws;
    auto carve = [&](size_t bytes) {
        void* q = (void*)p;
        p += (bytes + 255) & ~(size_t)255;
        return q;
    };
    unsigned* hb        = (unsigned*)carve((size_t)N * 64 * 4);     // h bf16 pairs
    unsigned* zb        = (unsigned*)carve((size_t)N * 64 * 4);     // z bf16 pairs
    unsigned short* WcT = (unsigned short*)carve(128 * 128 * 2);    // W_conv^T bf16
    unsigned short* WT  = (unsigned short*)carve(48 * 128 * 2);     // W_fc^T bf16
    float* dinv         = (float*)carve((size_t)N * 4);
    int*   gh           = (int*)carve((size_t)nb * NHB * 4);        // [bin][blk] counts->prefix
    int*   binsum       = (int*)carve((size_t)MAXNB * 4);
    long long* sorted   = (long long*)carve((size_t)E * 8);         // bucketed (dst,src)
    int*   bsrc         = (int*)carve((size_t)E * 4);               // compact CSR payload
    int*   rowptr       = (int*)carve((size_t)(N + 1) * 4);

    // K1: histogram (LDS atomics only) + weight prep — no memset needed anywhere
    k_hist<<<NHB + 1, 256, 0, stream>>>(edst, gh, nb, E, epb, Wc, Wfc, WcT, WT);
    // K2: parallel 3-phase exclusive scan of (bin,blk) counts
    k_scan_a<<<nb, 256, 0, stream>>>(gh, binsum, nb);
    k_scan_b<<<1, 512, 0, stream>>>(binsum, nb);
    k_scan_c<<<nb, 256, 0, stream>>>(gh, binsum, nb);
    // K3: race-free bucket scatter (LDS cursors) | gemm1 MFMA backfill
    int g1 = (N + 127) / 128;
    k_fat<<<NHB + g1, 256, 0, stream>>>(esrc, edst, gh, sorted, x, WcT, hb, nb, E, epb, N);
    // K4: per-bucket in-LDS counting sort -> compact CSR + dinv
    k_csr<<<nb, 256, 0, stream>>>(sorted, gh, bsrc, rowptr, dinv, nb, N, E);

    aggregate<<<((size_t)N * 64 + 255) / 256, 256, 0, stream>>>(
        hb, x, rowptr, bsrc, dinv, bc, gamma, beta, zb, N);

    gemm2<<<(N / 64 + 4) / 4, 256, 0, stream>>>((const unsigned short*)zb, WT, bfc, out, N);
}